// Round 8
// baseline (571.833 us; speedup 1.0000x reference)
//
#include <hip/hip_runtime.h>
#include <hip/hip_bf16.h>
#include <math.h>

// Problem constants (B=4, S=4096, D=4096, E=64, TOP_K=2)
constexpr int M_TOK = 16384;   // B*S tokens
constexpr int K_DIM = 4096;    // D
constexpr int NE    = 64;      // experts
constexpr int BM    = 64;      // tokens per block
constexpr int BK    = 64;      // K tile
constexpr int NT    = K_DIM / BK;
constexpr int APAD  = 4;       // +4 floats: row stride 272B -> A-tile reads 2-way (free), was 4-way

// d_out layout (flat float32): weights[2*M_TOK] | indices-as-float[2*M_TOK] | loss[1]
// d_ws  layout (float32): probs_colsum[64] | topk_count[64] | lse2_sum[1]

__global__ __launch_bounds__(256, 1)
void router_main(const float* __restrict__ A, const float* __restrict__ W,
                 float* __restrict__ out, float* __restrict__ gsums)
{
    __shared__ float As[BM][BK + APAD];  // 17 KB, token-major, padded
    __shared__ float Ws[BK][NE];         // 16 KB, k-major (same layout as global W)
    __shared__ float Ls[BM][NE + 1];     // logits then unnormalized probs; +1 pad
    __shared__ float sInv[BM];           // 1/sum_exp per token
    __shared__ float sCnt[NE];           // top-2 hit counts per expert

    const int tid = threadIdx.x;
    const int m0  = blockIdx.x * BM;

    // staging mapping: thread -> (row sr + 16q, 4 floats at col sc)
    const int sr = tid >> 4;            // 0..15
    const int sc = (tid & 15) << 2;     // 0..60

    // compute mapping: 16x16 thread grid, 4x4 micro-tile
    const int tr = (tid >> 4) << 2;     // token row quad
    const int tc = (tid & 15) << 2;     // expert col quad

    const float* aBase = A + (size_t)(m0 + sr) * K_DIM + sc;
    const float* wBase = W + (size_t)sr * NE + sc;

    float4 pa[4], pw[4];
    #pragma unroll
    for (int q = 0; q < 4; ++q) {
        pa[q] = *reinterpret_cast<const float4*>(aBase + (size_t)16 * q * K_DIM);
        pw[q] = *reinterpret_cast<const float4*>(wBase + 16 * q * NE);
    }

    // outer accumulator in f64: cross-tile rounding ~1e-7 on logits, protects
    // top-2 index outputs (1.26 absmax threshold) against near-tie flips.
    double acc[4][4] = {};

    for (int kt = 0; kt < NT; ++kt) {
        // write staged tile to LDS
        #pragma unroll
        for (int q = 0; q < 4; ++q) {
            *reinterpret_cast<float4*>(&As[sr + 16 * q][sc]) = pa[q];
            *reinterpret_cast<float4*>(&Ws[sr + 16 * q][sc]) = pw[q];
        }
        __syncthreads();

        // prefetch next tile into registers (overlaps with compute below)
        if (kt + 1 < NT) {
            const float* aN = aBase + (size_t)(kt + 1) * BK;
            const float* wN = wBase + (size_t)(kt + 1) * BK * NE;
            #pragma unroll
            for (int q = 0; q < 4; ++q) {
                pa[q] = *reinterpret_cast<const float4*>(aN + (size_t)16 * q * K_DIM);
                pw[q] = *reinterpret_cast<const float4*>(wN + 16 * q * NE);
            }
        }

        // two-level accumulation: fp32 tile-local accumulator
        float tacc[4][4] = {};
        #pragma unroll 4
        for (int k0 = 0; k0 < BK; k0 += 4) {
            float a_[4][4], b_[4][4];
            #pragma unroll
            for (int i = 0; i < 4; ++i)
                *reinterpret_cast<float4*>(a_[i]) =
                    *reinterpret_cast<const float4*>(&As[tr + i][k0]);
            #pragma unroll
            for (int kk = 0; kk < 4; ++kk)
                *reinterpret_cast<float4*>(b_[kk]) =
                    *reinterpret_cast<const float4*>(&Ws[k0 + kk][tc]);
            #pragma unroll
            for (int i = 0; i < 4; ++i)
                #pragma unroll
                for (int kk = 0; kk < 4; ++kk)
                    #pragma unroll
                    for (int j = 0; j < 4; ++j)
                        tacc[i][j] = fmaf(a_[i][kk], b_[kk][j], tacc[i][j]);
        }
        #pragma unroll
        for (int i = 0; i < 4; ++i)
            #pragma unroll
            for (int j = 0; j < 4; ++j)
                acc[i][j] += (double)tacc[i][j];
        __syncthreads();   // tile fully consumed before next ds_write
    }

    // ---- epilogue: logits -> LDS ----
    #pragma unroll
    for (int i = 0; i < 4; ++i)
        #pragma unroll
        for (int j = 0; j < 4; ++j)
            Ls[tr + i][tc + j] = (float)acc[i][j];

    if (tid < NE) sCnt[tid] = 0.0f;
    __syncthreads();

    // phase 1: wave 0, one thread per token
    float lse2 = 0.0f;
    if (tid < BM) {
        float* row = Ls[tid];
        float mx = row[0];
        #pragma unroll
        for (int e = 1; e < NE; ++e) mx = fmaxf(mx, row[e]);

        float s = 0.0f;
        float v1 = -INFINITY, v2 = -INFINITY;
        int   i1 = 0, i2 = 0;
        #pragma unroll
        for (int e = 0; e < NE; ++e) {
            float l  = row[e];
            float ex = expf(l - mx);
            row[e] = ex;            // keep unnormalized probs for column sums
            s += ex;
            if (l > v1)      { v2 = v1; i2 = i1; v1 = l; i1 = e; }
            else if (l > v2) { v2 = l;  i2 = e; }
        }
        float inv = 1.0f / s;
        sInv[tid] = inv;

        float p1 = expf(v1 - mx) * inv;
        float p2 = expf(v2 - mx) * inv;
        float denom = p1 + p2 + 1e-9f;
        const int t = m0 + tid;
        out[2 * t]               = p1 / denom;
        out[2 * t + 1]           = p2 / denom;
        out[2 * M_TOK + 2 * t]     = (float)i1;
        out[2 * M_TOK + 2 * t + 1] = (float)i2;

        float lse = mx + logf(s);
        lse2 = lse * lse;

        atomicAdd(&sCnt[i1], 1.0f);
        atomicAdd(&sCnt[i2], 1.0f);
    }
    // wave-0 reduction of lse^2 (threads 0..63 are exactly wave 0)
    if (tid < 64) {
        #pragma unroll
        for (int off = 32; off > 0; off >>= 1)
            lse2 += __shfl_down(lse2, off, 64);
        if (tid == 0) atomicAdd(&gsums[2 * NE], lse2);
    }
    __syncthreads();

    // phase 2: one thread per expert, column sums of probs + counts
    if (tid < NE) {
        float colsum = 0.0f;
        #pragma unroll
        for (int t = 0; t < BM; ++t)
            colsum += Ls[t][tid] * sInv[t];
        atomicAdd(&gsums[tid], colsum);
        atomicAdd(&gsums[NE + tid], sCnt[tid]);
    }
}

__global__ void router_loss(const float* __restrict__ gsums, float* __restrict__ out)
{
    const int e = threadIdx.x;   // 64 threads
    const float invM = 1.0f / (float)M_TOK;
    float frac  = gsums[NE + e] * invM;
    float pmean = gsums[e] * invM;
    float term  = frac * pmean;
    #pragma unroll
    for (int off = 32; off > 0; off >>= 1)
        term += __shfl_down(term, off, 64);
    if (e == 0) {
        float loss = gsums[2 * NE] * invM + (float)NE * term;
        out[4 * M_TOK] = loss;
    }
}

extern "C" void kernel_launch(void* const* d_in, const int* in_sizes, int n_in,
                              void* d_out, int out_size, void* d_ws, size_t ws_size,
                              hipStream_t stream)
{
    const float* A = (const float*)d_in[0];   // inputs [4,4096,4096]
    const float* W = (const float*)d_in[1];   // W [4096,64]
    float* out   = (float*)d_out;
    float* gsums = (float*)d_ws;

    hipMemsetAsync(gsums, 0, (2 * NE + 1) * sizeof(float), stream);
    router_main<<<M_TOK / BM, 256, 0, stream>>>(A, W, out, gsums);
    router_loss<<<1, 64, 0, stream>>>(gsums, out);
}